// Round 1
// baseline (158.300 us; speedup 1.0000x reference)
//
#include <hip/hip_runtime.h>
#include <cstdint>

#define B_ 16
#define N_ 2048
#define D_ 256
#define EPS_ 1e-9f

#define AS1 __attribute__((address_space(1)))
#define AS3 __attribute__((address_space(3)))

typedef float f4 __attribute__((ext_vector_type(4)));

__device__ float blockReduceSum(float x, float* red){
  int tid = threadIdx.x;
  red[tid] = x; __syncthreads();
  #pragma unroll
  for (int off = 128; off > 0; off >>= 1){
    if (tid < off) red[tid] += red[tid + off];
    __syncthreads();
  }
  float r = red[0]; __syncthreads();
  return r;
}

// fp32 norm + fp8(e4m3) conversion; 4 rows/wave, 16 rows/block (one batch/block).
// Emits race-free per-block partials Ppart/npart for tail's fast path.
// Also inits cost/currency/dmin/out (no separate memset dispatch).
__global__ __launch_bounds__(256) void prep_kernel(
    const float* __restrict__ preds, const float* __restrict__ labels,
    unsigned char* __restrict__ pa8, unsigned char* __restrict__ pb8,
    float* __restrict__ pn, float* __restrict__ ln,
    float* __restrict__ cost, float* __restrict__ currency,
    int* __restrict__ dmin, float* __restrict__ Ppart,
    float* __restrict__ npart, float* __restrict__ out){
  int s = blockIdx.y;
  int tid = threadIdx.x;
  if (s == 0){
    int i = blockIdx.x * 256 + tid;
    if (i < B_ * N_){ cost[i] = 1.f; currency[i] = 1.f; }
    if (i < B_) dmin[i] = 0x7f7fffff;  // FLT_MAX bits
    if (i == 0) out[0] = 0.f;
  }
  const float* src = s ? labels : preds;
  unsigned char* dst = s ? pb8 : pa8;
  float* norms = s ? ln : pn;
  int w = tid >> 6, lane = tid & 63;
  size_t row0 = (size_t)blockIdx.x * 16 + (size_t)w * 4;
  float4 v[4];
  #pragma unroll
  for (int q = 0; q < 4; q++)
    v[q] = ((const float4*)(src + (row0 + q) * D_))[lane];
  __shared__ f4 part[4][64];
  __shared__ float nred[4];
  f4 s4;
  s4[0] = v[0].x + v[1].x + v[2].x + v[3].x;
  s4[1] = v[0].y + v[1].y + v[2].y + v[3].y;
  s4[2] = v[0].z + v[1].z + v[2].z + v[3].z;
  s4[3] = v[0].w + v[1].w + v[2].w + v[3].w;
  float nsum = 0.f;
  #pragma unroll
  for (int q = 0; q < 4; q++){
    float sum = v[q].x*v[q].x + v[q].y*v[q].y + v[q].z*v[q].z + v[q].w*v[q].w;
    #pragma unroll
    for (int off = 32; off >= 1; off >>= 1) sum += __shfl_xor(sum, off);
    if (lane == 0){ norms[row0 + q] = sum; nsum += sum; }
    int pk = 0;
    pk = __builtin_amdgcn_cvt_pk_fp8_f32(v[q].x, v[q].y, pk, false); // bytes 0,1
    pk = __builtin_amdgcn_cvt_pk_fp8_f32(v[q].z, v[q].w, pk, true);  // bytes 2,3
    ((unsigned int*)(dst + (row0 + q) * D_))[lane] = (unsigned int)pk;
  }
  part[w][lane] = s4;
  if (lane == 0) nred[w] = nsum;
  __syncthreads();
  if (tid < 64){
    f4 t = part[0][tid];
    #pragma unroll
    for (int q = 1; q < 4; q++){
      t[0] += part[q][tid][0]; t[1] += part[q][tid][1];
      t[2] += part[q][tid][2]; t[3] += part[q][tid][3];
    }
    *(f4*)(Ppart + ((size_t)s * 2048 + blockIdx.x) * 256 + tid * 4) = t;
  }
  if (tid == 0)
    npart[s * 2048 + blockIdx.x] = nred[0] + nred[1] + nred[2] + nred[3];
}

// d[b][n][m] = pn[n] + ln[m] - 2*dot via FP8 MFMA; NO stores — only per-batch min.
// Round-12 restructure: 128x128 tile, 256 threads (4 waves, 64x64 wave tiles),
// BK=128 kept -> rows stay 128 BYTES so the proven conflict-free staging
// geometry (XOR r&7 on 16-B chunks, global-side swizzle, ds_read_b64
// fragments) is byte-identical to the verified 256x256 version. LDS halves to
// 64 KB -> 2 blocks/CU: with only 2 K-iterations the 2-phase vmcnt(0)+barrier
// drain is fully exposed at 1 block/CU; a second resident block's MFMAs
// co-schedule with the drain (m114 overlap). 4096 blocks = 8 staggered
// rounds/CU; per-XCD working set 2 MB fp8 -> L2-resident; tm-fastest keeps
// the B-panel L2-hot. dmin feeds only the skip certificate (guard 16 covers
// fp8 quantization error).
__global__ __launch_bounds__(256, 2) void gemm_minmax(
    const unsigned char* __restrict__ pa, const unsigned char* __restrict__ pbm,
    const float* __restrict__ pn, const float* __restrict__ ln,
    int* __restrict__ dmin)
{
  int lid = blockIdx.x;              // 4096 blocks, round-robin over 8 XCDs
  int l = lid >> 3;                  // 0..511 sequential per XCD
  int b = 2 * (lid & 7) + (l >> 8);  // 2 batches per XCD
  int t = l & 255;                   // 256 tiles of 128x128 per batch
  int tm = (t & 15) * 128, tn = (t >> 4) * 128;  // tm fastest: B-panel stays L2-hot
  const unsigned char* A  = pa  + (size_t)b * N_ * D_;
  const unsigned char* Bm = pbm + (size_t)b * N_ * D_;
  __shared__ __align__(16) unsigned char As[2][128 * 128];
  __shared__ __align__(16) unsigned char Bs[2][128 * 128];
  __shared__ float minred[4];
  int tid = threadIdx.x, lane = tid & 63, w = tid >> 6;
  int wm = (w >> 1) * 64, wn = (w & 1) * 64;
  int quad = lane >> 4, l15 = lane & 15;

  f4 acc[4][4];
  #pragma unroll
  for (int i = 0; i < 4; i++)
    #pragma unroll
    for (int j = 0; j < 4; j++) acc[i][j] = (f4)0.f;

  int lr = lane >> 3, ch = lane & 7;
  int gch = (ch ^ lr) * 16;          // byte offset; XOR swizzle on the GLOBAL side

  // prefetch k-chunk 0 into buffer 0 (rows are 128 B: 8 rows per wave-issue)
  #pragma unroll
  for (int p = 0; p < 4; p++){
    int R = p * 32 + w * 8;
    int r = R + lr;
    __builtin_amdgcn_global_load_lds(
        (const AS1 unsigned int*)(const void*)&A[(size_t)(tm + r) * D_ + gch],
        (AS3 unsigned int*)(void*)&As[0][R * 128], 16, 0, 0);
    __builtin_amdgcn_global_load_lds(
        (const AS1 unsigned int*)(const void*)&Bm[(size_t)(tn + r) * D_ + gch],
        (AS3 unsigned int*)(void*)&Bs[0][R * 128], 16, 0, 0);
  }

  int buf = 0;
  for (int ki = 0; ki < 2; ki++){
    __syncthreads();   // drains buf's loads (issued one compute-phase ago)
    if (ki < 1){
      int kt = 128;
      #pragma unroll
      for (int p = 0; p < 4; p++){
        int R = p * 32 + w * 8;
        int r = R + lr;
        __builtin_amdgcn_global_load_lds(
            (const AS1 unsigned int*)(const void*)&A[(size_t)(tm + r) * D_ + kt + gch],
            (AS3 unsigned int*)(void*)&As[buf ^ 1][R * 128], 16, 0, 0);
        __builtin_amdgcn_global_load_lds(
            (const AS1 unsigned int*)(const void*)&Bm[(size_t)(tn + r) * D_ + kt + gch],
            (AS3 unsigned int*)(void*)&Bs[buf ^ 1][R * 128], 16, 0, 0);
      }
    }
    #pragma unroll
    for (int s = 0; s < 4; s++){
      long af[4], bf[4];
      int base = s * 2 + (quad >> 1);     // logical 16-B chunk of k = s*32+quad*8
      int sub = (quad & 1) * 8;
      #pragma unroll
      for (int i = 0; i < 4; i++){
        int ra = wm + i * 16 + l15;
        af[i] = *(const long*)(&As[buf][ra * 128 + ((base ^ (ra & 7)) * 16) + sub]);
      }
      #pragma unroll
      for (int jj = 0; jj < 4; jj++){
        int rb = wn + jj * 16 + l15;
        bf[jj] = *(const long*)(&Bs[buf][rb * 128 + ((base ^ (rb & 7)) * 16) + sub]);
      }
      #pragma unroll
      for (int i = 0; i < 4; i++)
        #pragma unroll
        for (int jj = 0; jj < 4; jj++)
          acc[i][jj] = __builtin_amdgcn_mfma_f32_16x16x32_fp8_fp8(af[i], bf[jj], acc[i][jj], 0, 0, 0);
    }
    buf ^= 1;
  }

  // epilogue: pn/ln loaded AFTER the K-loop (pre-loop preload = spill bomb).
  // C/D layout col = lane&15, row = quad*4 + reg (dtype-independent, verified).
  float4 pnr[4];
  float lnr[4];
  #pragma unroll
  for (int i = 0; i < 4; i++)
    pnr[i] = *(const float4*)&pn[(size_t)b * N_ + tm + wm + i * 16 + quad * 4];
  #pragma unroll
  for (int jj = 0; jj < 4; jj++)
    lnr[jj] = ln[(size_t)b * N_ + tn + wn + jj * 16 + l15];

  float mind = 3.4e38f;
  #pragma unroll
  for (int i = 0; i < 4; i++){
    float pv[4] = {pnr[i].x, pnr[i].y, pnr[i].z, pnr[i].w};
    #pragma unroll
    for (int jj = 0; jj < 4; jj++){
      #pragma unroll
      for (int reg = 0; reg < 4; reg++){
        float v = pv[reg] + lnr[jj] - 2.f * acc[i][jj][reg];
        mind = fminf(mind, v);
      }
    }
  }
  #pragma unroll
  for (int off = 32; off >= 1; off >>= 1) mind = fminf(mind, __shfl_xor(mind, off));
  if (lane == 0) minred[w] = mind;
  __syncthreads();
  if (tid == 0){
    float m = minred[0];
    #pragma unroll
    for (int q = 1; q < 4; q++) m = fminf(m, minred[q]);
    atomicMin(&dmin[b], __float_as_int(fmaxf(m, 0.f)));
  }
}

// Merged tail: (1) exact fallback for the 6 negative exp-factors (each skipped
// when provably negligible: B*N^2*dmax*e^{ef*dmin}/EPS < 1e-3 iff
// ef*(dmin-16) < -55; guard 16 covers fp8 dot quantization error, |err|<~8
// at 5-sigma over 4M pairs; gating monotone — if ef=-0.25 skips, all skip);
// (2) the ef=0 term. FAST PATH (all skipped -> cost == currency == 1 exactly):
// alpha = 1/2048 exactly, bw = 1, term = sum|p|^2 + sum|l|^2 - (sum p).(sum l)/1024
// from prep's fp32 partials. SLOW PATH (dead here): exact from fp32 originals.
__global__ __launch_bounds__(256) void tail(
    const float* __restrict__ preds, const float* __restrict__ labels,
    const float* __restrict__ pn, const float* __restrict__ ln,
    float* __restrict__ cost, float* __restrict__ currency,
    const int* __restrict__ dmin, const float* __restrict__ Ppart,
    const float* __restrict__ npart, float* __restrict__ out)
{
  const float EF[6] = {-256.f, -64.f, -16.f, -4.f, -1.f, -0.25f};
  int b = blockIdx.x, tid = threadIdx.x;
  float dm = __int_as_float(dmin[b]);
  __shared__ float red[256];

  if (-0.25f * (dm - 16.f) < -55.f){
    // ---- fast path: all 6 negative iterations certified negligible ----
    float Pc = 0.f, Lc = 0.f;
    for (int k = 0; k < 128; k++){
      Pc += Ppart[((size_t)b * 128 + k) * 256 + tid];
      Lc += Ppart[((size_t)(2048 + b * 128 + k)) * 256 + tid];
    }
    float np = (tid < 128) ? npart[b * 128 + tid] : 0.f;
    float nl = (tid < 128) ? npart[2048 + b * 128 + tid] : 0.f;
    float Spn = blockReduceSum(np, red);
    float Sln = blockReduceSum(nl, red);
    float dot = blockReduceSum(Pc * Lc, red);
    if (tid == 0) atomicAdd(out, Spn + Sln - dot * (1.f / 1024.f));
    return;
  }

  // ---- slow exact path from fp32 originals (not expected to execute) ----
  __shared__ float alpha_l[N_];
  __shared__ float prow[D_];
  const float* A  = preds  + (size_t)b * N_ * D_;
  const float* Bm = labels + (size_t)b * N_ * D_;
  const float* pnb = pn + (size_t)b * N_;
  const float* lnb = ln + (size_t)b * N_;
  float* costb = cost + (size_t)b * N_;
  float* curb  = currency + (size_t)b * N_;
  for (int it = 0; it < 6; it++){
    float ef = EF[it];
    if (ef * (dm - 16.f) < -55.f) continue;
    float cost_c[8], colsum_c[8], bw_c[8], costnew_c[8];
    #pragma unroll
    for (int j = 0; j < 8; j++){ cost_c[j] = costb[j*256+tid]; colsum_c[j] = 0.f; }
    for (int r = 0; r < N_; r++){
      prow[tid] = A[(size_t)r * D_ + tid];
      __syncthreads();
      float s_c[8], rs = 0.f;
      for (int j = 0; j < 8; j++){
        int m = j*256+tid; float dot = 0.f;
        for (int k = 0; k < D_; k++) dot += prow[k] * Bm[(size_t)m * D_ + k];
        float d = pnb[r] + lnb[m] - 2.f*dot;
        float s = __expf(ef * d) * cost_c[j];
        s_c[j] = s; rs += s;
      }
      float tot = blockReduceSum(rs, red);
      float a = curb[r] / (tot + EPS_);
      if (tid == 0) alpha_l[r] = a;
      #pragma unroll
      for (int j = 0; j < 8; j++) colsum_c[j] += s_c[j] * a;
      __syncthreads();
    }
    #pragma unroll
    for (int j = 0; j < 8; j++){
      float cs = colsum_c[j];
      float bw = fminf(cost_c[j] / (cs + EPS_), 1.f);
      bw_c[j] = bw; costnew_c[j] = fmaxf(cost_c[j] - bw*cs, 0.f);
    }
    float contrib = 0.f;
    for (int r = 0; r < N_; r++){
      prow[tid] = A[(size_t)r * D_ + tid];
      __syncthreads();
      float a = alpha_l[r], rbs = 0.f;
      for (int j = 0; j < 8; j++){
        int m = j*256+tid; float dot = 0.f;
        for (int k = 0; k < D_; k++) dot += prow[k] * Bm[(size_t)m * D_ + k];
        float d = pnb[r] + lnb[m] - 2.f*dot;
        float bid = __expf(ef * d) * cost_c[j] * a * bw_c[j];
        rbs += bid; contrib += bid * d;
      }
      float tot = blockReduceSum(rbs, red);
      if (tid == 0) curb[r] = fmaxf(curb[r] - tot, 0.f);
      __syncthreads();
    }
    #pragma unroll
    for (int j = 0; j < 8; j++) costb[j*256+tid] = costnew_c[j];
    float ctot = blockReduceSum(contrib, red);
    if (tid == 0) atomicAdd(out, ctot);
    __syncthreads();
  }
  // ef=0 closed form with the general state (exact):
  float s = 0.f;
  #pragma unroll
  for (int j = 0; j < 8; j++) s += costb[j*256+tid];
  float Sc = blockReduceSum(s, red);
  float sa = 0.f, spn = 0.f;
  #pragma unroll
  for (int j = 0; j < 8; j++){
    int i = j*256+tid;
    float a = curb[i] / (Sc + EPS_);
    alpha_l[i] = a; sa += a; spn += a * pnb[i];
  }
  float Sa  = blockReduceSum(sa, red);
  float Spn = blockReduceSum(spn, red);
  float Pc = 0.f;
  for (int r = 0; r < N_; r++)
    Pc += alpha_l[r] * A[(size_t)r * D_ + tid];
  __syncthreads();
  float sv = 0.f, sln = 0.f;
  #pragma unroll
  for (int j = 0; j < 8; j++){
    int i = j*256+tid;
    float c = costb[i];
    float bw = fminf(c / (c * Sa + EPS_), 1.f);
    float vv = c * bw;
    alpha_l[i] = vv; sv += vv; sln += vv * lnb[i];
  }
  float Sv  = blockReduceSum(sv, red);
  float Sln = blockReduceSum(sln, red);
  float Lc = 0.f;
  for (int m = 0; m < N_; m++)
    Lc += alpha_l[m] * Bm[(size_t)m * D_ + tid];
  float dot = blockReduceSum(Pc * Lc, red);
  if (tid == 0) atomicAdd(out, Spn * Sv + Sa * Sln - 2.f * dot);
}

extern "C" void kernel_launch(void* const* d_in, const int* in_sizes, int n_in,
                              void* d_out, int out_size, void* d_ws, size_t ws_size,
                              hipStream_t stream)
{
  const float* preds  = (const float*)d_in[0];
  const float* labels = (const float*)d_in[1];
  float* out = (float*)d_out;
  char* ws = (char*)d_ws;
  const size_t BN = (size_t)B_ * N_;
  size_t off = 0;
  float* cost     = (float*)(ws + off); off += BN * 4;
  float* currency = (float*)(ws + off); off += BN * 4;
  float* pn       = (float*)(ws + off); off += BN * 4;
  float* ln       = (float*)(ws + off); off += BN * 4;
  int*   dmin     = (int*)(ws + off);   off += 256;
  float* npart    = (float*)(ws + off); off += (size_t)2 * 2048 * 4;
  float* Ppart    = (float*)(ws + off); off += (size_t)2 * 2048 * 256 * 4;
  unsigned char* pa8 = (unsigned char*)(ws + off); off += BN * D_;
  unsigned char* pb8 = (unsigned char*)(ws + off); off += BN * D_;

  prep_kernel<<<dim3((unsigned)(BN / 16), 2), 256, 0, stream>>>(
      preds, labels, pa8, pb8, pn, ln, cost, currency, dmin, Ppart, npart, out);
  gemm_minmax<<<dim3(4096), 256, 0, stream>>>(pa8, pb8, pn, ln, dmin);
  tail<<<dim3(B_), 256, 0, stream>>>(preds, labels, pn, ln, cost, currency, dmin,
                                     Ppart, npart, out);
}

// Round 2
// 136.923 us; speedup vs baseline: 1.1561x; 1.1561x over previous
//
#include <hip/hip_runtime.h>
#include <cstdint>

#define B_ 16
#define N_ 2048
#define D_ 256
#define EPS_ 1e-9f

#define AS1 __attribute__((address_space(1)))
#define AS3 __attribute__((address_space(3)))

typedef float f4 __attribute__((ext_vector_type(4)));

__device__ float blockReduceSum(float x, float* red){
  int tid = threadIdx.x;
  red[tid] = x; __syncthreads();
  #pragma unroll
  for (int off = 128; off > 0; off >>= 1){
    if (tid < off) red[tid] += red[tid + off];
    __syncthreads();
  }
  float r = red[0]; __syncthreads();
  return r;
}

// fp32 norm + fp8(e4m3) conversion; 4 rows/wave, 16 rows/block (one batch/block).
// Emits race-free per-block partials Ppart/npart for tail's fast path.
// Also inits cost/currency/dmin/out (no separate memset dispatch).
__global__ __launch_bounds__(256) void prep_kernel(
    const float* __restrict__ preds, const float* __restrict__ labels,
    unsigned char* __restrict__ pa8, unsigned char* __restrict__ pb8,
    float* __restrict__ pn, float* __restrict__ ln,
    float* __restrict__ cost, float* __restrict__ currency,
    int* __restrict__ dmin, float* __restrict__ Ppart,
    float* __restrict__ npart, float* __restrict__ out){
  int s = blockIdx.y;
  int tid = threadIdx.x;
  if (s == 0){
    int i = blockIdx.x * 256 + tid;
    if (i < B_ * N_){ cost[i] = 1.f; currency[i] = 1.f; }
    if (i < B_) dmin[i] = 0x7f7fffff;  // FLT_MAX bits
    if (i == 0) out[0] = 0.f;
  }
  const float* src = s ? labels : preds;
  unsigned char* dst = s ? pb8 : pa8;
  float* norms = s ? ln : pn;
  int w = tid >> 6, lane = tid & 63;
  size_t row0 = (size_t)blockIdx.x * 16 + (size_t)w * 4;
  float4 v[4];
  #pragma unroll
  for (int q = 0; q < 4; q++)
    v[q] = ((const float4*)(src + (row0 + q) * D_))[lane];
  __shared__ f4 part[4][64];
  __shared__ float nred[4];
  f4 s4;
  s4[0] = v[0].x + v[1].x + v[2].x + v[3].x;
  s4[1] = v[0].y + v[1].y + v[2].y + v[3].y;
  s4[2] = v[0].z + v[1].z + v[2].z + v[3].z;
  s4[3] = v[0].w + v[1].w + v[2].w + v[3].w;
  float nsum = 0.f;
  #pragma unroll
  for (int q = 0; q < 4; q++){
    float sum = v[q].x*v[q].x + v[q].y*v[q].y + v[q].z*v[q].z + v[q].w*v[q].w;
    #pragma unroll
    for (int off = 32; off >= 1; off >>= 1) sum += __shfl_xor(sum, off);
    if (lane == 0){ norms[row0 + q] = sum; nsum += sum; }
    int pk = 0;
    pk = __builtin_amdgcn_cvt_pk_fp8_f32(v[q].x, v[q].y, pk, false); // bytes 0,1
    pk = __builtin_amdgcn_cvt_pk_fp8_f32(v[q].z, v[q].w, pk, true);  // bytes 2,3
    ((unsigned int*)(dst + (row0 + q) * D_))[lane] = (unsigned int)pk;
  }
  part[w][lane] = s4;
  if (lane == 0) nred[w] = nsum;
  __syncthreads();
  if (tid < 64){
    f4 t = part[0][tid];
    #pragma unroll
    for (int q = 1; q < 4; q++){
      t[0] += part[q][tid][0]; t[1] += part[q][tid][1];
      t[2] += part[q][tid][2]; t[3] += part[q][tid][3];
    }
    *(f4*)(Ppart + ((size_t)s * 2048 + blockIdx.x) * 256 + tid * 4) = t;
  }
  if (tid == 0)
    npart[s * 2048 + blockIdx.x] = nred[0] + nred[1] + nred[2] + nred[3];
}

// d[b][n][m] = pn[n] + ln[m] - 2*dot via FP8 MFMA; NO stores — only per-batch min.
// Round-13: PANEL-RESIDENT B. Round-1 showed gemm is bound by staged L2->LDS
// bytes (268 MB @ 128^2 tiles = 55.9us; 134 MB @ 256^2 <= 41us), so maximize
// reuse per staged byte: each block keeps a full 256x256-B fp8 B-panel (64 KB)
// in LDS for its lifetime and walks FOUR 256-row A-tiles along tm with a
// 2x32 KB A double-buffer. Staged bytes: 134 -> 80 MB (-40%), wave-issues
// 131K -> 82K. Inner loop, XOR r&7 swizzle (A rows 128 B; B rows 256 B, same
// chunk^(r&7) involution, bank floor preserved), fragments, and C/D epilogue
// mapping carried verbatim from the verified 256^2 kernel. Grid 256 = 1
// block/CU (128 KB LDS); 2 batches/XCD = 2 MB, L2-resident. Min accumulated
// in-register across tiles; one atomicMin per block. dmin feeds only the skip
// certificate (guard 16 covers fp8 quantization error).
__global__ __launch_bounds__(512, 2) void gemm_minmax(
    const unsigned char* __restrict__ pa, const unsigned char* __restrict__ pbm,
    const float* __restrict__ pn, const float* __restrict__ ln,
    int* __restrict__ dmin)
{
  int lid = blockIdx.x;              // 256 blocks, round-robin over 8 XCDs
  int xcd = lid & 7;
  int l = lid >> 3;                  // 0..31 sequential per XCD
  int b = 2 * xcd + (l >> 4);        // 2 batches per XCD
  int p = l & 15;                    // 8 tn-panels x 2 tm-halves
  int tn = (p & 7) * 256;
  int tmb = (p >> 3) * 1024;         // tiles t=0..3 -> tm = tmb + t*256
  const unsigned char* A  = pa  + (size_t)b * N_ * D_;
  const unsigned char* Bm = pbm + (size_t)b * N_ * D_;
  __shared__ __align__(16) unsigned char Bs[256 * 256];     // 64 KB, resident
  __shared__ __align__(16) unsigned char As[2][256 * 128];  // 2 x 32 KB dbuf
  __shared__ float minred[8];
  int tid = threadIdx.x, lane = tid & 63, w = tid >> 6;
  int wm = (w >> 2) * 128, wn = (w & 3) * 64;
  int quad = lane >> 4, l15 = lane & 15;

  // ---- prologue staging ----
  // B panel: 256 rows x 256 B; one issue = 4 rows (lane>>4) x 16 chunks (lane&15).
  {
    int rB = lane >> 4;
    int c  = lane & 15;
    #pragma unroll
    for (int q = 0; q < 8; q++){
      int R = q * 32 + w * 4;
      int r = R + rB;
      int gc = c ^ (r & 7);          // global-side XOR swizzle (involution)
      __builtin_amdgcn_global_load_lds(
          (const AS1 unsigned int*)(const void*)&Bm[(size_t)(tn + r) * D_ + gc * 16],
          (AS3 unsigned int*)(void*)&Bs[R * 256 + lane * 16], 16, 0, 0);
    }
  }
  int lr = lane >> 3, ch = lane & 7;
  int gch = (ch ^ lr) * 16;          // A rows are 128-B halves: 8 rows/issue
  // A tile 0, K-half 0 -> As[0]
  #pragma unroll
  for (int pq = 0; pq < 4; pq++){
    int R = pq * 64 + w * 8;
    __builtin_amdgcn_global_load_lds(
        (const AS1 unsigned int*)(const void*)&A[(size_t)(tmb + R + lr) * D_ + gch],
        (AS3 unsigned int*)(void*)&As[0][R * 128], 16, 0, 0);
  }

  f4 acc[8][4];
  #pragma unroll
  for (int i = 0; i < 8; i++)
    #pragma unroll
    for (int j = 0; j < 4; j++) acc[i][j] = (f4)0.f;

  float mind = 3.4e38f;
  float lnr[4];
  #pragma unroll
  for (int jj = 0; jj < 4; jj++)
    lnr[jj] = ln[(size_t)b * N_ + tn + wn + jj * 16 + l15];

  int buf = 0;
  for (int step = 0; step < 8; step++){        // 4 tiles x 2 K-halves
    __syncthreads();   // drains As[buf]'s loads (issued one phase ago) + Bs at step 0
    if (step < 7){
      int t1 = (step + 1) >> 1, k1 = (step + 1) & 1;
      #pragma unroll
      for (int pq = 0; pq < 4; pq++){
        int R = pq * 64 + w * 8;
        __builtin_amdgcn_global_load_lds(
            (const AS1 unsigned int*)(const void*)&A[(size_t)(tmb + t1 * 256 + R + lr) * D_ + k1 * 128 + gch],
            (AS3 unsigned int*)(void*)&As[buf ^ 1][R * 128], 16, 0, 0);
      }
    }
    int ki = step & 1;
    #pragma unroll
    for (int s = 0; s < 4; s++){
      long af[8], bf[4];
      int base = s * 2 + (quad >> 1);     // logical 16-B chunk of k = s*32+quad*8
      int sub = (quad & 1) * 8;
      #pragma unroll
      for (int i = 0; i < 8; i++){
        int ra = wm + i * 16 + l15;
        af[i] = *(const long*)(&As[buf][ra * 128 + ((base ^ (ra & 7)) * 16) + sub]);
      }
      int gB = ki * 8 + base;             // chunk within the 256-B B row
      #pragma unroll
      for (int jj = 0; jj < 4; jj++){
        int rb = wn + jj * 16 + l15;
        bf[jj] = *(const long*)(&Bs[rb * 256 + ((gB ^ (rb & 7)) * 16) + sub]);
      }
      #pragma unroll
      for (int i = 0; i < 8; i++)
        #pragma unroll
        for (int jj = 0; jj < 4; jj++)
          acc[i][jj] = __builtin_amdgcn_mfma_f32_16x16x32_fp8_fp8(af[i], bf[jj], acc[i][jj], 0, 0, 0);
    }
    if (ki == 1){
      // per-tile epilogue: C/D layout col = lane&15, row = quad*4 + reg.
      int t = step >> 1;
      int tm = tmb + t * 256;
      float4 pnr[8];
      #pragma unroll
      for (int i = 0; i < 8; i++)
        pnr[i] = *(const float4*)&pn[(size_t)b * N_ + tm + wm + i * 16 + quad * 4];
      #pragma unroll
      for (int i = 0; i < 8; i++){
        float pv[4] = {pnr[i].x, pnr[i].y, pnr[i].z, pnr[i].w};
        #pragma unroll
        for (int jj = 0; jj < 4; jj++){
          #pragma unroll
          for (int reg = 0; reg < 4; reg++){
            float v = pv[reg] + lnr[jj] - 2.f * acc[i][jj][reg];
            mind = fminf(mind, v);
            acc[i][jj][reg] = 0.f;      // rezero for next tile
          }
        }
      }
    }
    buf ^= 1;
  }

  #pragma unroll
  for (int off = 32; off >= 1; off >>= 1) mind = fminf(mind, __shfl_xor(mind, off));
  if (lane == 0) minred[w] = mind;
  __syncthreads();
  if (tid == 0){
    float m = minred[0];
    #pragma unroll
    for (int q = 1; q < 8; q++) m = fminf(m, minred[q]);
    atomicMin(&dmin[b], __float_as_int(fmaxf(m, 0.f)));
  }
}

// Merged tail: (1) exact fallback for the 6 negative exp-factors (each skipped
// when provably negligible: B*N^2*dmax*e^{ef*dmin}/EPS < 1e-3 iff
// ef*(dmin-16) < -55; guard 16 covers fp8 dot quantization error, |err|<~8
// at 5-sigma over 4M pairs; gating monotone — if ef=-0.25 skips, all skip);
// (2) the ef=0 term. FAST PATH (all skipped -> cost == currency == 1 exactly):
// alpha = 1/2048 exactly, bw = 1, term = sum|p|^2 + sum|l|^2 - (sum p).(sum l)/1024
// from prep's fp32 partials. SLOW PATH (dead here): exact from fp32 originals.
__global__ __launch_bounds__(256) void tail(
    const float* __restrict__ preds, const float* __restrict__ labels,
    const float* __restrict__ pn, const float* __restrict__ ln,
    float* __restrict__ cost, float* __restrict__ currency,
    const int* __restrict__ dmin, const float* __restrict__ Ppart,
    const float* __restrict__ npart, float* __restrict__ out)
{
  const float EF[6] = {-256.f, -64.f, -16.f, -4.f, -1.f, -0.25f};
  int b = blockIdx.x, tid = threadIdx.x;
  float dm = __int_as_float(dmin[b]);
  __shared__ float red[256];

  if (-0.25f * (dm - 16.f) < -55.f){
    // ---- fast path: all 6 negative iterations certified negligible ----
    float Pc = 0.f, Lc = 0.f;
    for (int k = 0; k < 128; k++){
      Pc += Ppart[((size_t)b * 128 + k) * 256 + tid];
      Lc += Ppart[((size_t)(2048 + b * 128 + k)) * 256 + tid];
    }
    float np = (tid < 128) ? npart[b * 128 + tid] : 0.f;
    float nl = (tid < 128) ? npart[2048 + b * 128 + tid] : 0.f;
    float Spn = blockReduceSum(np, red);
    float Sln = blockReduceSum(nl, red);
    float dot = blockReduceSum(Pc * Lc, red);
    if (tid == 0) atomicAdd(out, Spn + Sln - dot * (1.f / 1024.f));
    return;
  }

  // ---- slow exact path from fp32 originals (not expected to execute) ----
  __shared__ float alpha_l[N_];
  __shared__ float prow[D_];
  const float* A  = preds  + (size_t)b * N_ * D_;
  const float* Bm = labels + (size_t)b * N_ * D_;
  const float* pnb = pn + (size_t)b * N_;
  const float* lnb = ln + (size_t)b * N_;
  float* costb = cost + (size_t)b * N_;
  float* curb  = currency + (size_t)b * N_;
  for (int it = 0; it < 6; it++){
    float ef = EF[it];
    if (ef * (dm - 16.f) < -55.f) continue;
    float cost_c[8], colsum_c[8], bw_c[8], costnew_c[8];
    #pragma unroll
    for (int j = 0; j < 8; j++){ cost_c[j] = costb[j*256+tid]; colsum_c[j] = 0.f; }
    for (int r = 0; r < N_; r++){
      prow[tid] = A[(size_t)r * D_ + tid];
      __syncthreads();
      float s_c[8], rs = 0.f;
      for (int j = 0; j < 8; j++){
        int m = j*256+tid; float dot = 0.f;
        for (int k = 0; k < D_; k++) dot += prow[k] * Bm[(size_t)m * D_ + k];
        float d = pnb[r] + lnb[m] - 2.f*dot;
        float s = __expf(ef * d) * cost_c[j];
        s_c[j] = s; rs += s;
      }
      float tot = blockReduceSum(rs, red);
      float a = curb[r] / (tot + EPS_);
      if (tid == 0) alpha_l[r] = a;
      #pragma unroll
      for (int j = 0; j < 8; j++) colsum_c[j] += s_c[j] * a;
      __syncthreads();
    }
    #pragma unroll
    for (int j = 0; j < 8; j++){
      float cs = colsum_c[j];
      float bw = fminf(cost_c[j] / (cs + EPS_), 1.f);
      bw_c[j] = bw; costnew_c[j] = fmaxf(cost_c[j] - bw*cs, 0.f);
    }
    float contrib = 0.f;
    for (int r = 0; r < N_; r++){
      prow[tid] = A[(size_t)r * D_ + tid];
      __syncthreads();
      float a = alpha_l[r], rbs = 0.f;
      for (int j = 0; j < 8; j++){
        int m = j*256+tid; float dot = 0.f;
        for (int k = 0; k < D_; k++) dot += prow[k] * Bm[(size_t)m * D_ + k];
        float d = pnb[r] + lnb[m] - 2.f*dot;
        float bid = __expf(ef * d) * cost_c[j] * a * bw_c[j];
        rbs += bid; contrib += bid * d;
      }
      float tot = blockReduceSum(rbs, red);
      if (tid == 0) curb[r] = fmaxf(curb[r] - tot, 0.f);
      __syncthreads();
    }
    #pragma unroll
    for (int j = 0; j < 8; j++) costb[j*256+tid] = costnew_c[j];
    float ctot = blockReduceSum(contrib, red);
    if (tid == 0) atomicAdd(out, ctot);
    __syncthreads();
  }
  // ef=0 closed form with the general state (exact):
  float s = 0.f;
  #pragma unroll
  for (int j = 0; j < 8; j++) s += costb[j*256+tid];
  float Sc = blockReduceSum(s, red);
  float sa = 0.f, spn = 0.f;
  #pragma unroll
  for (int j = 0; j < 8; j++){
    int i = j*256+tid;
    float a = curb[i] / (Sc + EPS_);
    alpha_l[i] = a; sa += a; spn += a * pnb[i];
  }
  float Sa  = blockReduceSum(sa, red);
  float Spn = blockReduceSum(spn, red);
  float Pc = 0.f;
  for (int r = 0; r < N_; r++)
    Pc += alpha_l[r] * A[(size_t)r * D_ + tid];
  __syncthreads();
  float sv = 0.f, sln = 0.f;
  #pragma unroll
  for (int j = 0; j < 8; j++){
    int i = j*256+tid;
    float c = costb[i];
    float bw = fminf(c / (c * Sa + EPS_), 1.f);
    float vv = c * bw;
    alpha_l[i] = vv; sv += vv; sln += vv * lnb[i];
  }
  float Sv  = blockReduceSum(sv, red);
  float Sln = blockReduceSum(sln, red);
  float Lc = 0.f;
  for (int m = 0; m < N_; m++)
    Lc += alpha_l[m] * Bm[(size_t)m * D_ + tid];
  float dot = blockReduceSum(Pc * Lc, red);
  if (tid == 0) atomicAdd(out, Spn * Sv + Sa * Sln - 2.f * dot);
}

extern "C" void kernel_launch(void* const* d_in, const int* in_sizes, int n_in,
                              void* d_out, int out_size, void* d_ws, size_t ws_size,
                              hipStream_t stream)
{
  const float* preds  = (const float*)d_in[0];
  const float* labels = (const float*)d_in[1];
  float* out = (float*)d_out;
  char* ws = (char*)d_ws;
  const size_t BN = (size_t)B_ * N_;
  size_t off = 0;
  float* cost     = (float*)(ws + off); off += BN * 4;
  float* currency = (float*)(ws + off); off += BN * 4;
  float* pn       = (float*)(ws + off); off += BN * 4;
  float* ln       = (float*)(ws + off); off += BN * 4;
  int*   dmin     = (int*)(ws + off);   off += 256;
  float* npart    = (float*)(ws + off); off += (size_t)2 * 2048 * 4;
  float* Ppart    = (float*)(ws + off); off += (size_t)2 * 2048 * 256 * 4;
  unsigned char* pa8 = (unsigned char*)(ws + off); off += BN * D_;
  unsigned char* pb8 = (unsigned char*)(ws + off); off += BN * D_;

  prep_kernel<<<dim3((unsigned)(BN / 16), 2), 256, 0, stream>>>(
      preds, labels, pa8, pb8, pn, ln, cost, currency, dmin, Ppart, npart, out);
  gemm_minmax<<<dim3(256), 512, 0, stream>>>(pa8, pb8, pn, ln, dmin);
  tail<<<dim3(B_), 256, 0, stream>>>(preds, labels, pn, ln, cost, currency, dmin,
                                     Ppart, npart, out);
}